// Round 9
// baseline (133.524 us; speedup 1.0000x reference)
//
#include <hip/hip_runtime.h>
#include <math.h>

#define D_BINS 59
#define CO     64
#define CI     256
#define NB     4
#define NC     6
#define H_IMG  16
#define W_IMG  44
#define HW     704            // H_IMG * W_IMG
#define NPIX   (NB*NC*HW)     // 16896
#define XD     128
#define YD     128
#define ZD     7
#define NOUT   123            // D_BINS + CO
#define PXB    132            // pixels per k_head tile: 16896 = 128 * 132
#define THR    384            // k_head threads: 6 waves
#define XW     66             // X row width (64 cols + 2 pad)

typedef float v2f __attribute__((ext_vector_type(2)));

// ---------------------------------------------------------------------------
// Double-precision rigid-transform inverse (matches np.linalg.inv to ~1e-15,
// avoiding depth-bin boundary flips downstream).
// ---------------------------------------------------------------------------
__device__ void inv_rigid(const float* __restrict__ M, float* __restrict__ o) {
    double a = M[0], b = M[1], c = M[2], t0 = M[3];
    double d = M[4], e = M[5], f = M[6], t1 = M[7];
    double g = M[8], h = M[9], ii = M[10], t2 = M[11];
    double A00 = e*ii - f*h, A01 = c*h - b*ii, A02 = b*f - c*e;
    double A10 = f*g - d*ii, A11 = a*ii - c*g, A12 = c*d - a*f;
    double A20 = d*h - e*g,  A21 = b*g - a*h,  A22 = a*e - b*d;
    double det = a*A00 + b*A10 + c*A20;
    double inv = 1.0 / det;
    double r00 = A00*inv, r01 = A01*inv, r02 = A02*inv;
    double r10 = A10*inv, r11 = A11*inv, r12 = A12*inv;
    double r20 = A20*inv, r21 = A21*inv, r22 = A22*inv;
    o[0] = (float)r00; o[1] = (float)r01; o[2]  = (float)r02;
    o[3] = (float)(-(r00*t0 + r01*t1 + r02*t2));
    o[4] = (float)r10; o[5] = (float)r11; o[6]  = (float)r12;
    o[7] = (float)(-(r10*t0 + r11*t1 + r12*t2));
    o[8] = (float)r20; o[9] = (float)r21; o[10] = (float)r22;
    o[11] = (float)(-(r20*t0 + r21*t1 + r22*t2));
}

// ---------------------------------------------------------------------------
// Kernel 1: prep. W (123x256) -> wt2, k-pair-interleaved + transposed:
//   wt2[(k/2)*256 + o*2 + (k&1)], o zero-padded to 128. Unchanged.
// ---------------------------------------------------------------------------
__global__ __launch_bounds__(256) void k_pre(
    const float* __restrict__ wd, const float* __restrict__ c2e,
    float* __restrict__ wt2, float* __restrict__ e2c) {
    const int o = blockIdx.x;   // 0..127
    const int k = threadIdx.x;  // 0..255
    float v = (o < NOUT) ? wd[(size_t)o * CI + k] : 0.f;
    wt2[(size_t)(k >> 1) * 256 + o * 2 + (k & 1)] = v;
    if (blockIdx.x == 0 && k < NB * NC)
        inv_rigid(c2e + k * 16, e2c + k * 12);
}

// ---------------------------------------------------------------------------
// Kernel 2: depth/feat head. NEW this round: 2 PIXELS PER LANE.
// Ledger: 6 structures all land 35-45 us; every one needs 128 B of W per
// 32 cyc of FMA per wave, and R6 showed more waves make it worse (scalar
// path queueing; s_loads can't pipeline past ~2 steps in the SGPR file).
// If each k2 step exposes s cycles of W stall, T ~ steps*(FMA+s). Fix:
// double FMA per step at the SAME W traffic. Tile = 132 px (16896=128*132),
// grid (128,2); main lanes carry px {ln, ln+64} (2x ds_read_b64, 2-way
// bank-free), 32 v2f accs; edge waves 4/5 take columns 128..131 (2 each).
// Per k2: 16 s_load-v2f of W + 32 pk_fma (was 16). Block count halves ->
// half the wave streams contending for K$/L2. X[132][66] unions with A
// (35.4 KB LDS). Per-pixel FMA order bit-identical to R4.
// ---------------------------------------------------------------------------
__global__ __launch_bounds__(THR) void k_head(
    const float* __restrict__ img, const float* __restrict__ wt2,
    const float* __restrict__ bd, float* __restrict__ depth_out,
    float* __restrict__ feat_ws) {
    __shared__ float smem[PXB * XW + PXB];   // A[32kp][264] (8448) | X (8712); S
    float* S = smem + PXB * XW;

    const int tid  = threadIdx.x;
    const int wv   = tid >> 6;               // 0..5
    const int ln   = tid & 63;
    const int p0   = blockIdx.x * PXB;
    const int ob   = (int)blockIdx.y << 6;   // 0 or 64
    const bool is_main = (wv < 4);
    const int o0   = __builtin_amdgcn_readfirstlane(ob + ((is_main ? wv : 0) << 4));
    const int e0   = 128 + (wv - 4);         // edge cols (wave 4: 128/130,
    const int e1   = 130 + (wv - 4);         //            wave 5: 129/131)

    v2f accA[16], accB[16];                  // main: px ln / px ln+64
#pragma unroll
    for (int j = 0; j < 16; ++j) { accA[j] = (v2f)(0.f); accB[j] = (v2f)(0.f); }
    v2f acc2a = (v2f)(0.f), acc2b = (v2f)(0.f);   // edge cols e0 / e1

    float* A = smem;
    for (int kc = 0; kc < 4; ++kc) {
        // ---- stage A chunk: 64 ch x 132 px, kp-interleaved; 22*384=8448 ----
#pragma unroll
        for (int it = 0; it < 22; ++it) {
            int idx = tid + it * THR;
            int kl = idx / PXB, px = idx - kl * PXB;
            int p = p0 + px;
            int bn = p / HW, hw = p - bn * HW;
            A[(kl >> 1) * 264 + px * 2 + (kl & 1)] =
                img[((size_t)bn * CI + kc * 64 + kl) * HW + hw];
        }
        __syncthreads();

        if (is_main) {
#pragma unroll 4
            for (int k2 = 0; k2 < 32; ++k2) {
                v2f aA = *(const v2f*)(A + k2 * 264 + ln * 2);        // 2-way: free
                v2f aB = *(const v2f*)(A + k2 * 264 + (ln + 64) * 2);
                const v2f* w =
                    (const v2f*)(wt2 + (size_t)(kc * 32 + k2) * 256) + o0; // s_load
#pragma unroll
                for (int j = 0; j < 16; ++j) {
                    v2f wj = w[j];
                    accA[j] = __builtin_elementwise_fma(aA, wj, accA[j]);
                    accB[j] = __builtin_elementwise_fma(aB, wj, accB[j]);
                }
            }
        } else {
#pragma unroll 4
            for (int k2 = 0; k2 < 32; ++k2) {
                v2f a0 = *(const v2f*)(A + k2 * 264 + e0 * 2);  // broadcast
                v2f a1 = *(const v2f*)(A + k2 * 264 + e1 * 2);
                const float* w = wt2 + (size_t)(kc * 32 + k2) * 256;
                v2f w0 = {w[(ob + ln) * 2], w[(ob + ln) * 2 + 1]};  // dwordx2
                acc2a = __builtin_elementwise_fma(a0, w0, acc2a);
                acc2b = __builtin_elementwise_fma(a1, w0, acc2b);
            }
        }
        __syncthreads();
    }

    // ---- epilogue into X[132][XW], col = o - ob (0..63); X aliases A ----
    float* X = smem;
    if (is_main) {
#pragma unroll
        for (int j = 0; j < 16; ++j) {
            int o = o0 + j;
            if (o < NOUT) {
                int col = o - ob;
                X[ln * XW + col]        = (accA[j].x + accA[j].y) + bd[o];
                X[(ln + 64) * XW + col] = (accB[j].x + accB[j].y) + bd[o];
            }
        }
    } else {
        int o = ob + ln;
        if (o < NOUT) {
            int col = o - ob;   // = ln
            X[e0 * XW + col] = (acc2a.x + acc2a.y) + bd[o];
            X[e1 * XW + col] = (acc2b.x + acc2b.y) + bd[o];
        }
    }
    __syncthreads();

    if (blockIdx.y == 0) {
        // feat channels 0..4 (o = 59..63)
        for (int g = tid; g < PXB * 5; g += THR) {
            int p = g / 5, c = g - p * 5;
            feat_ws[(size_t)(p0 + p) * CO + c] = X[p * XW + 59 + c];
        }
        // softmax over cols 0..58, one thread per pixel
        if (tid < PXB) {
            float* row = X + tid * XW;
            float m = row[0];
            for (int o = 1; o < D_BINS; ++o) m = fmaxf(m, row[o]);
            float s = 0.f;
            for (int o = 0; o < D_BINS; ++o) {
                float e = __expf(row[o] - m);
                row[o] = e;
                s += e;
            }
            S[tid] = 1.f / s;
        }
        __syncthreads();
        // depth: tile region contiguous [p0*59, (p0+132)*59) -> coalesced
        for (int g = tid; g < PXB * D_BINS; g += THR) {
            int p = g / D_BINS;
            int o = g - p * D_BINS;
            depth_out[(size_t)p0 * D_BINS + g] = X[p * XW + o] * S[p];
        }
    } else {
        // feat channels 5..63 (o = 64..122 at cols 0..58)
        for (int g = tid; g < PXB * D_BINS; g += THR) {
            int p = g / D_BINS;
            int col = g - p * D_BINS;
            feat_ws[(size_t)(p0 + p) * CO + 5 + col] = X[p * XW + col];
        }
    }
}

// ---------------------------------------------------------------------------
// Kernel 3: project voxels, gather depth weight + feat, splat to BEV.
// Round-0 (124 us baseline) version, byte-identical.
// ---------------------------------------------------------------------------
__global__ __launch_bounds__(256) void k_splat(
    const float* __restrict__ e2c, const float* __restrict__ Kmat,
    const float* __restrict__ depth_g, const float* __restrict__ feat_ws,
    float* __restrict__ bev) {
    __shared__ int   hw_s[ZD][64];
    __shared__ float wgt_s[ZD][64];

    const int tx = threadIdx.x;          // 0..63 -> x
    const int cq = threadIdx.y;          // 0..3  -> channel quarter / z-slice
    const int x = blockIdx.x * 64 + tx;
    const int y = blockIdx.y;
    const int b = blockIdx.z;
    const float wx = (float)x * 0.8f + (-51.2f);
    const float wy = (float)y * 0.8f + (-51.2f);

    float acc[16];
#pragma unroll
    for (int m = 0; m < 16; ++m) acc[m] = 0.f;

    for (int n = 0; n < NC; ++n) {
        const int bn = b * NC + n;
        const float* E = e2c + bn * 12;
        const float* Km = Kmat + bn * 9;
        const float k00 = Km[0], k01 = Km[1], k02 = Km[2];
        const float k10 = Km[3], k11 = Km[4], k12 = Km[5];
        const float e02 = E[2], e12 = E[6], e22 = E[10];
        const float bx0 = E[0] * wx + E[1] * wy + E[3];
        const float bx1 = E[4] * wx + E[5] * wy + E[7];
        const float bx2 = E[8] * wx + E[9] * wy + E[11];

        // ---- projection phase: thread (tx,cq) owns z = cq and cq+4 ----
#pragma unroll
        for (int zz = 0; zz < 2; ++zz) {
            const int z = cq + zz * 4;
            if (z < ZD) {
                const float wz = -2.5f + (float)z;
                const float cx = bx0 + e02 * wz;
                const float cy = bx1 + e12 * wz;
                const float cz = bx2 + e22 * wz;
                const float zs = fmaxf(cz, 0.1f);
                const float rz = 1.0f / zs;         // IEEE divide
                const float xn = cx * rz;
                const float yn = cy * rz;
                const float fu = (k00 * xn + k01 * yn + k02) * 0.0625f;
                const float fv = (k10 * xn + k11 * yn + k12) * 0.0625f;
                const int bin = (int)(cz - 1.0f);   // trunc, matches astype(int32)
                const bool valid = (fu >= 0.f) & (fu < (float)W_IMG) &
                                   (fv >= 0.f) & (fv < (float)H_IMG) &
                                   (cz > 0.5f) & (bin >= 0) & (bin < D_BINS);
                int hw = -1;
                float wgt = 0.f;
                if (valid) {
                    int u = (int)fu;                // valid => in range
                    int v = (int)fv;
                    hw = v * W_IMG + u;
                    wgt = depth_g[((size_t)bn * HW + hw) * D_BINS + bin];
                }
                hw_s[z][tx] = hw;
                wgt_s[z][tx] = wgt;
            }
        }
        __syncthreads();

        // ---- accumulate phase: z ascending (same FMA order as baseline) ----
#pragma unroll
        for (int z = 0; z < ZD; ++z) {
            const int hw = hw_s[z][tx];       // 4 cq threads same addr: broadcast
            if (hw >= 0) {
                const float wgt = wgt_s[z][tx];
                const float4* fp =
                    (const float4*)(feat_ws + ((size_t)bn * HW + hw) * CO + cq * 16);
                float4 f0 = fp[0], f1 = fp[1], f2 = fp[2], f3 = fp[3];
                acc[0]  = fmaf(wgt, f0.x, acc[0]);
                acc[1]  = fmaf(wgt, f0.y, acc[1]);
                acc[2]  = fmaf(wgt, f0.z, acc[2]);
                acc[3]  = fmaf(wgt, f0.w, acc[3]);
                acc[4]  = fmaf(wgt, f1.x, acc[4]);
                acc[5]  = fmaf(wgt, f1.y, acc[5]);
                acc[6]  = fmaf(wgt, f1.z, acc[6]);
                acc[7]  = fmaf(wgt, f1.w, acc[7]);
                acc[8]  = fmaf(wgt, f2.x, acc[8]);
                acc[9]  = fmaf(wgt, f2.y, acc[9]);
                acc[10] = fmaf(wgt, f2.z, acc[10]);
                acc[11] = fmaf(wgt, f2.w, acc[11]);
                acc[12] = fmaf(wgt, f3.x, acc[12]);
                acc[13] = fmaf(wgt, f3.y, acc[13]);
                acc[14] = fmaf(wgt, f3.z, acc[14]);
                acc[15] = fmaf(wgt, f3.w, acc[15]);
            }
        }
        __syncthreads();   // LDS reused next n
    }
    // out[b][c][y][x], c = cq*16 + m; 64 lanes = consecutive x -> coalesced
    float* ob = bev + (((size_t)b * CO + cq * 16) * YD + y) * XD + x;
#pragma unroll
    for (int m = 0; m < 16; ++m) ob[(size_t)m * YD * XD] = acc[m];
}

extern "C" void kernel_launch(void* const* d_in, const int* in_sizes, int n_in,
                              void* d_out, int out_size, void* d_ws, size_t ws_size,
                              hipStream_t stream) {
    const float* img  = (const float*)d_in[0];  // (B,N,256,16,44)
    const float* c2e  = (const float*)d_in[1];  // (B,N,4,4)
    const float* Kmat = (const float*)d_in[2];  // (B,N,3,3)
    const float* wd   = (const float*)d_in[3];  // (123,256)
    const float* bd   = (const float*)d_in[4];  // (123,)
    float* bev = (float*)d_out;                         // (B,64,128,128)
    float* depth_out = bev + (size_t)NB * CO * YD * XD; // (B,N,16,44,59)
    float* feat_ws = (float*)d_ws;                      // NPIX*64 floats
    float* wt2 = feat_ws + (size_t)NPIX * CO;           // 128*256 floats
    float* e2c = wt2 + 128 * 256;                       // 24*12 floats

    k_pre<<<128, 256, 0, stream>>>(wd, c2e, wt2, e2c);
    k_head<<<dim3(128, 2), THR, 0, stream>>>(img, wt2, bd, depth_out, feat_ws);
    k_splat<<<dim3(2, YD, NB), dim3(64, 4, 1), 0, stream>>>(e2c, Kmat, depth_out,
                                                            feat_ws, bev);
}

// Round 10
// 126.778 us; speedup vs baseline: 1.0532x; 1.0532x over previous
//
#include <hip/hip_runtime.h>
#include <math.h>

#define D_BINS 59
#define CO     64
#define CI     256
#define NB     4
#define NC     6
#define H_IMG  16
#define W_IMG  44
#define HW     704            // H_IMG * W_IMG
#define NPIX   (NB*NC*HW)     // 16896
#define XD     128
#define YD     128
#define ZD     7
#define NOUT   123            // D_BINS + CO
#define PXB    66             // pixels per k_head block tile
#define THR    384            // k_head threads: 6 waves
#define XW     66             // X row width (64 cols + 2 pad)

typedef float v2f __attribute__((ext_vector_type(2)));

// ---------------------------------------------------------------------------
// Double-precision rigid-transform inverse (matches np.linalg.inv to ~1e-15,
// avoiding depth-bin boundary flips downstream).
// ---------------------------------------------------------------------------
__device__ void inv_rigid(const float* __restrict__ M, float* __restrict__ o) {
    double a = M[0], b = M[1], c = M[2], t0 = M[3];
    double d = M[4], e = M[5], f = M[6], t1 = M[7];
    double g = M[8], h = M[9], ii = M[10], t2 = M[11];
    double A00 = e*ii - f*h, A01 = c*h - b*ii, A02 = b*f - c*e;
    double A10 = f*g - d*ii, A11 = a*ii - c*g, A12 = c*d - a*f;
    double A20 = d*h - e*g,  A21 = b*g - a*h,  A22 = a*e - b*d;
    double det = a*A00 + b*A10 + c*A20;
    double inv = 1.0 / det;
    double r00 = A00*inv, r01 = A01*inv, r02 = A02*inv;
    double r10 = A10*inv, r11 = A11*inv, r12 = A12*inv;
    double r20 = A20*inv, r21 = A21*inv, r22 = A22*inv;
    o[0] = (float)r00; o[1] = (float)r01; o[2]  = (float)r02;
    o[3] = (float)(-(r00*t0 + r01*t1 + r02*t2));
    o[4] = (float)r10; o[5] = (float)r11; o[6]  = (float)r12;
    o[7] = (float)(-(r10*t0 + r11*t1 + r12*t2));
    o[8] = (float)r20; o[9] = (float)r21; o[10] = (float)r22;
    o[11] = (float)(-(r20*t0 + r21*t1 + r22*t2));
}

// ---------------------------------------------------------------------------
// Kernel 1: prep. W (123x256) -> wt2, k-pair-interleaved + transposed:
//   wt2[(k/2)*256 + o*2 + (k&1)], o zero-padded to 128. Unchanged.
// ---------------------------------------------------------------------------
__global__ __launch_bounds__(256) void k_pre(
    const float* __restrict__ wd, const float* __restrict__ c2e,
    float* __restrict__ wt2, float* __restrict__ e2c) {
    const int o = blockIdx.x;   // 0..127
    const int k = threadIdx.x;  // 0..255
    float v = (o < NOUT) ? wd[(size_t)o * CI + k] : 0.f;
    wt2[(size_t)(k >> 1) * 256 + o * 2 + (k & 1)] = v;
    if (blockIdx.x == 0 && k < NB * NC)
        inv_rigid(c2e + k * 16, e2c + k * 12);
}

// ---------------------------------------------------------------------------
// Kernel 2: depth/feat head. R4 structure (the 122.0 us best) EXACTLY,
// except the softmax: was 1 thread/pixel with a 59-step DEPENDENT LDS-read
// fmax chain + 59-step dependent exp/acc loop (~5-7 us serial tail, only
// 2 blocks/CU to hide it). Now wave-parallel: wave wv owns rows wv+6i
// (66 = 6x11); lanes 0..58 read one column (conflict-free), 6-step
// __shfl_xor butterfly for max (EXACT: max is order-independent) and sum
// (reassociated denominator ~1ulp; R6 proved reassociation passes).
// ---------------------------------------------------------------------------
__global__ __launch_bounds__(THR) void k_head(
    const float* __restrict__ img, const float* __restrict__ wt2,
    const float* __restrict__ bd, float* __restrict__ depth_out,
    float* __restrict__ feat_ws) {
    __shared__ float A[64 / 2 * 132];        // 4224: 32 kp rows x 132
    __shared__ float X[PXB * XW];            // 4356
    __shared__ float S[PXB];

    const int tid  = threadIdx.x;
    const int wv   = tid >> 6;               // 0..5
    const int ln   = tid & 63;
    const int p0   = blockIdx.x * PXB;
    const int half = blockIdx.y;             // 0 or 1
    const int ob   = half << 6;              // 0 or 64
    const bool is_main = (wv < 4);
    const int o0   = __builtin_amdgcn_readfirstlane(ob + ((is_main ? wv : 0) << 4));
    const int epx  = 64 + (wv - 4);          // edge wave's pixel column

    // ---- A staging addresses (kc-invariant): 4224 = 384 * 11 exactly ----
    int a_off[11];
    int g_off[11];
#pragma unroll
    for (int it = 0; it < 11; ++it) {
        int idx = tid + it * THR;            // < 4224 always
        int kl = idx / PXB, px = idx - kl * PXB;
        int p = p0 + px;
        int bn = p / HW, hw = p - bn * HW;
        a_off[it] = (kl >> 1) * 132 + px * 2 + (kl & 1);
        g_off[it] = (bn * CI + kl) * HW + hw;
    }

    v2f acc[16];                             // main: o-strip of 16
#pragma unroll
    for (int j = 0; j < 16; ++j) acc[j] = (v2f)(0.f);
    v2f acc2 = (v2f)(0.f);                   // edge: o = ob + ln

    for (int kc = 0; kc < 4; ++kc) {
#pragma unroll
        for (int it = 0; it < 11; ++it)
            A[a_off[it]] = img[g_off[it] + kc * 64 * HW];
        __syncthreads();

        if (is_main) {
#pragma unroll 4
            for (int k2 = 0; k2 < 32; ++k2) {
                v2f a = *(const v2f*)(A + k2 * 132 + ln * 2);  // stride-8B: free
                const v2f* w =
                    (const v2f*)(wt2 + (size_t)(kc * 32 + k2) * 256) + o0; // s_load
#pragma unroll
                for (int j = 0; j < 16; ++j)
                    acc[j] = __builtin_elementwise_fma(a, w[j], acc[j]);
            }
        } else {
#pragma unroll 4
            for (int k2 = 0; k2 < 32; ++k2) {
                v2f a = *(const v2f*)(A + k2 * 132 + epx * 2);  // broadcast
                const float* w = wt2 + (size_t)(kc * 32 + k2) * 256;
                v2f w0 = {w[(ob + ln) * 2], w[(ob + ln) * 2 + 1]};
                acc2 = __builtin_elementwise_fma(a, w0, acc2);
            }
        }
        __syncthreads();
    }

    // ---- epilogue into X[66][XW], col = o - ob (0..63) ----
    if (is_main) {
#pragma unroll
        for (int j = 0; j < 16; ++j) {
            int o = o0 + j;
            if (o < NOUT)
                X[ln * XW + (o - ob)] = (acc[j].x + acc[j].y) + bd[o];
        }
    } else {
        int o = ob + ln;
        if (o < NOUT)
            X[epx * XW + ln] = (acc2.x + acc2.y) + bd[o];
    }
    __syncthreads();

    if (half == 0) {
        // feat channels 0..4 (o = 59..63); disjoint cols from softmax (0..58)
        if (tid < PXB * 5) {
            int p = tid / 5, c = tid - p * 5;
            feat_ws[(size_t)(p0 + p) * CO + c] = X[p * XW + 59 + c];
        }
        // wave-parallel softmax: wave wv owns rows wv + 6*i (66 = 6*11)
#pragma unroll
        for (int i = 0; i < 11; ++i) {
            int r = wv + 6 * i;
            float* row = X + r * XW;
            float v = (ln < D_BINS) ? row[ln] : -3.0e38f;
#pragma unroll
            for (int m = 1; m < 64; m <<= 1)
                v = fmaxf(v, __shfl_xor(v, m, 64));    // exact max
            float e = 0.f;
            if (ln < D_BINS) {
                e = __expf(row[ln] - v);
                row[ln] = e;
            }
            float s = e;
#pragma unroll
            for (int m = 1; m < 64; m <<= 1)
                s += __shfl_xor(s, m, 64);             // reassociated sum
            if (ln == 0) S[r] = 1.f / s;
        }
        __syncthreads();
        // depth: block region contiguous [p0*59, (p0+66)*59) -> coalesced
        for (int g = tid; g < PXB * D_BINS; g += THR) {
            int p = g / D_BINS;
            int o = g - p * D_BINS;
            depth_out[(size_t)p0 * D_BINS + g] = X[p * XW + o] * S[p];
        }
    } else {
        // feat channels 5..63 (o = 64..122 at cols 0..58)
        for (int g = tid; g < PXB * D_BINS; g += THR) {
            int p = g / D_BINS;
            int col = g - p * D_BINS;
            feat_ws[(size_t)(p0 + p) * CO + 5 + col] = X[p * XW + col];
        }
    }
}

// ---------------------------------------------------------------------------
// Kernel 3: project voxels, gather depth weight + feat, splat to BEV.
// Round-0 version with ONE scheduling change: blockIdx.y -> y via the
// bijective band swizzle y = (by&3)*32 + (by>>2). Consecutive dispatch ids
// cycle XCDs on (bx, by%4); the swizzle makes each (bx, by%4) class -- i.e.
// each XCD -- own a CONTIGUOUS 32-row y band, shrinking its L2 working set
// of feat_ws/depth_g to the camera rows that band actually hits.
// Zero numerics change (pure remap; per-(x,y,c) math identical).
// ---------------------------------------------------------------------------
__global__ __launch_bounds__(256) void k_splat(
    const float* __restrict__ e2c, const float* __restrict__ Kmat,
    const float* __restrict__ depth_g, const float* __restrict__ feat_ws,
    float* __restrict__ bev) {
    __shared__ int   hw_s[ZD][64];
    __shared__ float wgt_s[ZD][64];

    const int tx = threadIdx.x;          // 0..63 -> x
    const int cq = threadIdx.y;          // 0..3  -> channel quarter / z-slice
    const int x = blockIdx.x * 64 + tx;
    const int y = ((blockIdx.y & 3) << 5) + (blockIdx.y >> 2);   // band swizzle
    const int b = blockIdx.z;
    const float wx = (float)x * 0.8f + (-51.2f);
    const float wy = (float)y * 0.8f + (-51.2f);

    float acc[16];
#pragma unroll
    for (int m = 0; m < 16; ++m) acc[m] = 0.f;

    for (int n = 0; n < NC; ++n) {
        const int bn = b * NC + n;
        const float* E = e2c + bn * 12;
        const float* Km = Kmat + bn * 9;
        const float k00 = Km[0], k01 = Km[1], k02 = Km[2];
        const float k10 = Km[3], k11 = Km[4], k12 = Km[5];
        const float e02 = E[2], e12 = E[6], e22 = E[10];
        const float bx0 = E[0] * wx + E[1] * wy + E[3];
        const float bx1 = E[4] * wx + E[5] * wy + E[7];
        const float bx2 = E[8] * wx + E[9] * wy + E[11];

        // ---- projection phase: thread (tx,cq) owns z = cq and cq+4 ----
#pragma unroll
        for (int zz = 0; zz < 2; ++zz) {
            const int z = cq + zz * 4;
            if (z < ZD) {
                const float wz = -2.5f + (float)z;
                const float cx = bx0 + e02 * wz;
                const float cy = bx1 + e12 * wz;
                const float cz = bx2 + e22 * wz;
                const float zs = fmaxf(cz, 0.1f);
                const float rz = 1.0f / zs;         // IEEE divide
                const float xn = cx * rz;
                const float yn = cy * rz;
                const float fu = (k00 * xn + k01 * yn + k02) * 0.0625f;
                const float fv = (k10 * xn + k11 * yn + k12) * 0.0625f;
                const int bin = (int)(cz - 1.0f);   // trunc, matches astype(int32)
                const bool valid = (fu >= 0.f) & (fu < (float)W_IMG) &
                                   (fv >= 0.f) & (fv < (float)H_IMG) &
                                   (cz > 0.5f) & (bin >= 0) & (bin < D_BINS);
                int hw = -1;
                float wgt = 0.f;
                if (valid) {
                    int u = (int)fu;                // valid => in range
                    int v = (int)fv;
                    hw = v * W_IMG + u;
                    wgt = depth_g[((size_t)bn * HW + hw) * D_BINS + bin];
                }
                hw_s[z][tx] = hw;
                wgt_s[z][tx] = wgt;
            }
        }
        __syncthreads();

        // ---- accumulate phase: z ascending (same FMA order as baseline) ----
#pragma unroll
        for (int z = 0; z < ZD; ++z) {
            const int hw = hw_s[z][tx];       // 4 cq threads same addr: broadcast
            if (hw >= 0) {
                const float wgt = wgt_s[z][tx];
                const float4* fp =
                    (const float4*)(feat_ws + ((size_t)bn * HW + hw) * CO + cq * 16);
                float4 f0 = fp[0], f1 = fp[1], f2 = fp[2], f3 = fp[3];
                acc[0]  = fmaf(wgt, f0.x, acc[0]);
                acc[1]  = fmaf(wgt, f0.y, acc[1]);
                acc[2]  = fmaf(wgt, f0.z, acc[2]);
                acc[3]  = fmaf(wgt, f0.w, acc[3]);
                acc[4]  = fmaf(wgt, f1.x, acc[4]);
                acc[5]  = fmaf(wgt, f1.y, acc[5]);
                acc[6]  = fmaf(wgt, f1.z, acc[6]);
                acc[7]  = fmaf(wgt, f1.w, acc[7]);
                acc[8]  = fmaf(wgt, f2.x, acc[8]);
                acc[9]  = fmaf(wgt, f2.y, acc[9]);
                acc[10] = fmaf(wgt, f2.z, acc[10]);
                acc[11] = fmaf(wgt, f2.w, acc[11]);
                acc[12] = fmaf(wgt, f3.x, acc[12]);
                acc[13] = fmaf(wgt, f3.y, acc[13]);
                acc[14] = fmaf(wgt, f3.z, acc[14]);
                acc[15] = fmaf(wgt, f3.w, acc[15]);
            }
        }
        __syncthreads();   // LDS reused next n
    }
    // out[b][c][y][x], c = cq*16 + m; 64 lanes = consecutive x -> coalesced
    float* ob = bev + (((size_t)b * CO + cq * 16) * YD + y) * XD + x;
#pragma unroll
    for (int m = 0; m < 16; ++m) ob[(size_t)m * YD * XD] = acc[m];
}

extern "C" void kernel_launch(void* const* d_in, const int* in_sizes, int n_in,
                              void* d_out, int out_size, void* d_ws, size_t ws_size,
                              hipStream_t stream) {
    const float* img  = (const float*)d_in[0];  // (B,N,256,16,44)
    const float* c2e  = (const float*)d_in[1];  // (B,N,4,4)
    const float* Kmat = (const float*)d_in[2];  // (B,N,3,3)
    const float* wd   = (const float*)d_in[3];  // (123,256)
    const float* bd   = (const float*)d_in[4];  // (123,)
    float* bev = (float*)d_out;                         // (B,64,128,128)
    float* depth_out = bev + (size_t)NB * CO * YD * XD; // (B,N,16,44,59)
    float* feat_ws = (float*)d_ws;                      // NPIX*64 floats
    float* wt2 = feat_ws + (size_t)NPIX * CO;           // 128*256 floats
    float* e2c = wt2 + 128 * 256;                       // 24*12 floats

    k_pre<<<128, 256, 0, stream>>>(wd, c2e, wt2, e2c);
    k_head<<<dim3(256, 2), THR, 0, stream>>>(img, wt2, bd, depth_out, feat_ws);
    k_splat<<<dim3(2, YD, NB), dim3(64, 4, 1), 0, stream>>>(e2c, Kmat, depth_out,
                                                            feat_ws, bev);
}

// Round 11
// 123.104 us; speedup vs baseline: 1.0846x; 1.0298x over previous
//
#include <hip/hip_runtime.h>
#include <math.h>

#define D_BINS 59
#define CO     64
#define CI     256
#define NB     4
#define NC     6
#define H_IMG  16
#define W_IMG  44
#define HW     704            // H_IMG * W_IMG
#define NPIX   (NB*NC*HW)     // 16896
#define XD     128
#define YD     128
#define ZD     7
#define NOUT   123            // D_BINS + CO
#define PXB    66             // pixels per k_head block tile
#define THR    384            // k_head threads: 6 waves
#define XW     66             // X row width (64 cols + 2 pad)

typedef float v2f __attribute__((ext_vector_type(2)));

// ---------------------------------------------------------------------------
// Double-precision rigid-transform inverse (matches np.linalg.inv to ~1e-15,
// avoiding depth-bin boundary flips downstream).
// ---------------------------------------------------------------------------
__device__ void inv_rigid(const float* __restrict__ M, float* __restrict__ o) {
    double a = M[0], b = M[1], c = M[2], t0 = M[3];
    double d = M[4], e = M[5], f = M[6], t1 = M[7];
    double g = M[8], h = M[9], ii = M[10], t2 = M[11];
    double A00 = e*ii - f*h, A01 = c*h - b*ii, A02 = b*f - c*e;
    double A10 = f*g - d*ii, A11 = a*ii - c*g, A12 = c*d - a*f;
    double A20 = d*h - e*g,  A21 = b*g - a*h,  A22 = a*e - b*d;
    double det = a*A00 + b*A10 + c*A20;
    double inv = 1.0 / det;
    double r00 = A00*inv, r01 = A01*inv, r02 = A02*inv;
    double r10 = A10*inv, r11 = A11*inv, r12 = A12*inv;
    double r20 = A20*inv, r21 = A21*inv, r22 = A22*inv;
    o[0] = (float)r00; o[1] = (float)r01; o[2]  = (float)r02;
    o[3] = (float)(-(r00*t0 + r01*t1 + r02*t2));
    o[4] = (float)r10; o[5] = (float)r11; o[6]  = (float)r12;
    o[7] = (float)(-(r10*t0 + r11*t1 + r12*t2));
    o[8] = (float)r20; o[9] = (float)r21; o[10] = (float)r22;
    o[11] = (float)(-(r20*t0 + r21*t1 + r22*t2));
}

// ---------------------------------------------------------------------------
// Kernel 1: prep. W (123x256) -> wt2, k-pair-interleaved + transposed:
//   wt2[(k/2)*256 + o*2 + (k&1)], o zero-padded to 128. Unchanged.
// ---------------------------------------------------------------------------
__global__ __launch_bounds__(256) void k_pre(
    const float* __restrict__ wd, const float* __restrict__ c2e,
    float* __restrict__ wt2, float* __restrict__ e2c) {
    const int o = blockIdx.x;   // 0..127
    const int k = threadIdx.x;  // 0..255
    float v = (o < NOUT) ? wd[(size_t)o * CI + k] : 0.f;
    wt2[(size_t)(k >> 1) * 256 + o * 2 + (k & 1)] = v;
    if (blockIdx.x == 0 && k < NB * NC)
        inv_rigid(c2e + k * 16, e2c + k * 12);
}

// ---------------------------------------------------------------------------
// Kernel 2: depth/feat head. R4 configuration, byte-identical (the 122.0 us
// best): OUTPUT-SPLIT, grid (256,2). half 0 computes o in [0,64) (all 59
// logits -> softmax + depth + feat ch 0..4); half 1 computes o in [64,128)
// (feat ch 5..63). Each block: 6 waves (4 main x o-strip 16, 2 edge px),
// 34.6 KB LDS -> 2 blocks/CU, two independent barrier domains per CU.
// W path: uniform pointer -> s_load via K$.
// ---------------------------------------------------------------------------
__global__ __launch_bounds__(THR) void k_head(
    const float* __restrict__ img, const float* __restrict__ wt2,
    const float* __restrict__ bd, float* __restrict__ depth_out,
    float* __restrict__ feat_ws) {
    __shared__ float A[64 / 2 * 132];        // 4224: 32 kp rows x 132
    __shared__ float X[PXB * XW];            // 4356
    __shared__ float S[PXB];

    const int tid  = threadIdx.x;
    const int wv   = tid >> 6;               // 0..5
    const int ln   = tid & 63;
    const int p0   = blockIdx.x * PXB;
    const int half = blockIdx.y;             // 0 or 1
    const int ob   = half << 6;              // 0 or 64
    const bool is_main = (wv < 4);
    const int o0   = __builtin_amdgcn_readfirstlane(ob + ((is_main ? wv : 0) << 4));
    const int epx  = 64 + (wv - 4);          // edge wave's pixel column

    // ---- A staging addresses (kc-invariant): 4224 = 384 * 11 exactly ----
    int a_off[11];
    int g_off[11];
#pragma unroll
    for (int it = 0; it < 11; ++it) {
        int idx = tid + it * THR;            // < 4224 always
        int kl = idx / PXB, px = idx - kl * PXB;
        int p = p0 + px;
        int bn = p / HW, hw = p - bn * HW;
        a_off[it] = (kl >> 1) * 132 + px * 2 + (kl & 1);
        g_off[it] = (bn * CI + kl) * HW + hw;
    }

    v2f acc[16];                             // main: o-strip of 16
#pragma unroll
    for (int j = 0; j < 16; ++j) acc[j] = (v2f)(0.f);
    v2f acc2 = (v2f)(0.f);                   // edge: o = ob + ln

    for (int kc = 0; kc < 4; ++kc) {
#pragma unroll
        for (int it = 0; it < 11; ++it)
            A[a_off[it]] = img[g_off[it] + kc * 64 * HW];
        __syncthreads();

        if (is_main) {
#pragma unroll 4
            for (int k2 = 0; k2 < 32; ++k2) {
                v2f a = *(const v2f*)(A + k2 * 132 + ln * 2);  // stride-8B: free
                const v2f* w =
                    (const v2f*)(wt2 + (size_t)(kc * 32 + k2) * 256) + o0; // s_load
#pragma unroll
                for (int j = 0; j < 16; ++j)
                    acc[j] = __builtin_elementwise_fma(a, w[j], acc[j]);
            }
        } else {
#pragma unroll 4
            for (int k2 = 0; k2 < 32; ++k2) {
                v2f a = *(const v2f*)(A + k2 * 132 + epx * 2);  // broadcast
                const float* w = wt2 + (size_t)(kc * 32 + k2) * 256;
                v2f w0 = {w[(ob + ln) * 2], w[(ob + ln) * 2 + 1]};
                acc2 = __builtin_elementwise_fma(a, w0, acc2);
            }
        }
        __syncthreads();
    }

    // ---- epilogue into X[66][XW], col = o - ob (0..63) ----
    if (is_main) {
#pragma unroll
        for (int j = 0; j < 16; ++j) {
            int o = o0 + j;
            if (o < NOUT)
                X[ln * XW + (o - ob)] = (acc[j].x + acc[j].y) + bd[o];
        }
    } else {
        int o = ob + ln;
        if (o < NOUT)
            X[epx * XW + ln] = (acc2.x + acc2.y) + bd[o];
    }
    __syncthreads();

    if (half == 0) {
        // feat channels 0..4 (o = 59..63)
        if (tid < PXB * 5) {
            int p = tid / 5, c = tid - p * 5;
            feat_ws[(size_t)(p0 + p) * CO + c] = X[p * XW + 59 + c];
        }
        // softmax over cols 0..58, one thread per pixel
        if (tid < PXB) {
            float* row = X + tid * XW;
            float m = row[0];
            for (int o = 1; o < D_BINS; ++o) m = fmaxf(m, row[o]);
            float s = 0.f;
            for (int o = 0; o < D_BINS; ++o) {
                float e = __expf(row[o] - m);
                row[o] = e;
                s += e;
            }
            S[tid] = 1.f / s;
        }
        __syncthreads();
        // depth: block region contiguous [p0*59, (p0+66)*59) -> coalesced
        for (int g = tid; g < PXB * D_BINS; g += THR) {
            int p = g / D_BINS;
            int o = g - p * D_BINS;
            depth_out[(size_t)p0 * D_BINS + g] = X[p * XW + o] * S[p];
        }
    } else {
        // feat channels 5..63 (o = 64..122 at cols 0..58)
        for (int g = tid; g < PXB * D_BINS; g += THR) {
            int p = g / D_BINS;
            int col = g - p * D_BINS;
            feat_ws[(size_t)(p0 + p) * CO + 5 + col] = X[p * XW + col];
        }
    }
}

// ---------------------------------------------------------------------------
// Kernel 3: project voxels, gather depth weight + feat, splat to BEV.
// Round-0 (124 us baseline) version, byte-identical.
// ---------------------------------------------------------------------------
__global__ __launch_bounds__(256) void k_splat(
    const float* __restrict__ e2c, const float* __restrict__ Kmat,
    const float* __restrict__ depth_g, const float* __restrict__ feat_ws,
    float* __restrict__ bev) {
    __shared__ int   hw_s[ZD][64];
    __shared__ float wgt_s[ZD][64];

    const int tx = threadIdx.x;          // 0..63 -> x
    const int cq = threadIdx.y;          // 0..3  -> channel quarter / z-slice
    const int x = blockIdx.x * 64 + tx;
    const int y = blockIdx.y;
    const int b = blockIdx.z;
    const float wx = (float)x * 0.8f + (-51.2f);
    const float wy = (float)y * 0.8f + (-51.2f);

    float acc[16];
#pragma unroll
    for (int m = 0; m < 16; ++m) acc[m] = 0.f;

    for (int n = 0; n < NC; ++n) {
        const int bn = b * NC + n;
        const float* E = e2c + bn * 12;
        const float* Km = Kmat + bn * 9;
        const float k00 = Km[0], k01 = Km[1], k02 = Km[2];
        const float k10 = Km[3], k11 = Km[4], k12 = Km[5];
        const float e02 = E[2], e12 = E[6], e22 = E[10];
        const float bx0 = E[0] * wx + E[1] * wy + E[3];
        const float bx1 = E[4] * wx + E[5] * wy + E[7];
        const float bx2 = E[8] * wx + E[9] * wy + E[11];

        // ---- projection phase: thread (tx,cq) owns z = cq and cq+4 ----
#pragma unroll
        for (int zz = 0; zz < 2; ++zz) {
            const int z = cq + zz * 4;
            if (z < ZD) {
                const float wz = -2.5f + (float)z;
                const float cx = bx0 + e02 * wz;
                const float cy = bx1 + e12 * wz;
                const float cz = bx2 + e22 * wz;
                const float zs = fmaxf(cz, 0.1f);
                const float rz = 1.0f / zs;         // IEEE divide
                const float xn = cx * rz;
                const float yn = cy * rz;
                const float fu = (k00 * xn + k01 * yn + k02) * 0.0625f;
                const float fv = (k10 * xn + k11 * yn + k12) * 0.0625f;
                const int bin = (int)(cz - 1.0f);   // trunc, matches astype(int32)
                const bool valid = (fu >= 0.f) & (fu < (float)W_IMG) &
                                   (fv >= 0.f) & (fv < (float)H_IMG) &
                                   (cz > 0.5f) & (bin >= 0) & (bin < D_BINS);
                int hw = -1;
                float wgt = 0.f;
                if (valid) {
                    int u = (int)fu;                // valid => in range
                    int v = (int)fv;
                    hw = v * W_IMG + u;
                    wgt = depth_g[((size_t)bn * HW + hw) * D_BINS + bin];
                }
                hw_s[z][tx] = hw;
                wgt_s[z][tx] = wgt;
            }
        }
        __syncthreads();

        // ---- accumulate phase: z ascending (same FMA order as baseline) ----
#pragma unroll
        for (int z = 0; z < ZD; ++z) {
            const int hw = hw_s[z][tx];       // 4 cq threads same addr: broadcast
            if (hw >= 0) {
                const float wgt = wgt_s[z][tx];
                const float4* fp =
                    (const float4*)(feat_ws + ((size_t)bn * HW + hw) * CO + cq * 16);
                float4 f0 = fp[0], f1 = fp[1], f2 = fp[2], f3 = fp[3];
                acc[0]  = fmaf(wgt, f0.x, acc[0]);
                acc[1]  = fmaf(wgt, f0.y, acc[1]);
                acc[2]  = fmaf(wgt, f0.z, acc[2]);
                acc[3]  = fmaf(wgt, f0.w, acc[3]);
                acc[4]  = fmaf(wgt, f1.x, acc[4]);
                acc[5]  = fmaf(wgt, f1.y, acc[5]);
                acc[6]  = fmaf(wgt, f1.z, acc[6]);
                acc[7]  = fmaf(wgt, f1.w, acc[7]);
                acc[8]  = fmaf(wgt, f2.x, acc[8]);
                acc[9]  = fmaf(wgt, f2.y, acc[9]);
                acc[10] = fmaf(wgt, f2.z, acc[10]);
                acc[11] = fmaf(wgt, f2.w, acc[11]);
                acc[12] = fmaf(wgt, f3.x, acc[12]);
                acc[13] = fmaf(wgt, f3.y, acc[13]);
                acc[14] = fmaf(wgt, f3.z, acc[14]);
                acc[15] = fmaf(wgt, f3.w, acc[15]);
            }
        }
        __syncthreads();   // LDS reused next n
    }
    // out[b][c][y][x], c = cq*16 + m; 64 lanes = consecutive x -> coalesced
    float* ob = bev + (((size_t)b * CO + cq * 16) * YD + y) * XD + x;
#pragma unroll
    for (int m = 0; m < 16; ++m) ob[(size_t)m * YD * XD] = acc[m];
}

extern "C" void kernel_launch(void* const* d_in, const int* in_sizes, int n_in,
                              void* d_out, int out_size, void* d_ws, size_t ws_size,
                              hipStream_t stream) {
    const float* img  = (const float*)d_in[0];  // (B,N,256,16,44)
    const float* c2e  = (const float*)d_in[1];  // (B,N,4,4)
    const float* Kmat = (const float*)d_in[2];  // (B,N,3,3)
    const float* wd   = (const float*)d_in[3];  // (123,256)
    const float* bd   = (const float*)d_in[4];  // (123,)
    float* bev = (float*)d_out;                         // (B,64,128,128)
    float* depth_out = bev + (size_t)NB * CO * YD * XD; // (B,N,16,44,59)
    float* feat_ws = (float*)d_ws;                      // NPIX*64 floats
    float* wt2 = feat_ws + (size_t)NPIX * CO;           // 128*256 floats
    float* e2c = wt2 + 128 * 256;                       // 24*12 floats

    k_pre<<<128, 256, 0, stream>>>(wd, c2e, wt2, e2c);
    k_head<<<dim3(256, 2), THR, 0, stream>>>(img, wt2, bd, depth_out, feat_ws);
    k_splat<<<dim3(2, YD, NB), dim3(64, 4, 1), 0, stream>>>(e2c, Kmat, depth_out,
                                                            feat_ws, bev);
}

// Round 12
// 120.920 us; speedup vs baseline: 1.1042x; 1.0181x over previous
//
#include <hip/hip_runtime.h>
#include <math.h>

#define D_BINS 59
#define CO     64
#define CI     256
#define NB     4
#define NC     6
#define H_IMG  16
#define W_IMG  44
#define HW     704            // H_IMG * W_IMG
#define NPIX   (NB*NC*HW)     // 16896
#define XD     128
#define YD     128
#define ZD     7
#define NOUT   123            // D_BINS + CO
#define PXB    66             // pixels per k_head block tile

typedef float v2f  __attribute__((ext_vector_type(2)));
typedef short short8 __attribute__((ext_vector_type(8)));
typedef float f32x4  __attribute__((ext_vector_type(4)));

// round-to-nearest-even fp32 -> bf16 (bit pattern), and back
__device__ inline unsigned short f2bf(float f) {
    unsigned u = __float_as_uint(f);
    return (unsigned short)((u + 0x7FFFu + ((u >> 16) & 1u)) >> 16);
}
__device__ inline float bf2f(unsigned short h) {
    return __uint_as_float((unsigned)h << 16);
}

// ---------------------------------------------------------------------------
// Double-precision rigid-transform inverse (matches np.linalg.inv to ~1e-15).
// ---------------------------------------------------------------------------
__device__ void inv_rigid(const float* __restrict__ M, float* __restrict__ o) {
    double a = M[0], b = M[1], c = M[2], t0 = M[3];
    double d = M[4], e = M[5], f = M[6], t1 = M[7];
    double g = M[8], h = M[9], ii = M[10], t2 = M[11];
    double A00 = e*ii - f*h, A01 = c*h - b*ii, A02 = b*f - c*e;
    double A10 = f*g - d*ii, A11 = a*ii - c*g, A12 = c*d - a*f;
    double A20 = d*h - e*g,  A21 = b*g - a*h,  A22 = a*e - b*d;
    double det = a*A00 + b*A10 + c*A20;
    double inv = 1.0 / det;
    double r00 = A00*inv, r01 = A01*inv, r02 = A02*inv;
    double r10 = A10*inv, r11 = A11*inv, r12 = A12*inv;
    double r20 = A20*inv, r21 = A21*inv, r22 = A22*inv;
    o[0] = (float)r00; o[1] = (float)r01; o[2]  = (float)r02;
    o[3] = (float)(-(r00*t0 + r01*t1 + r02*t2));
    o[4] = (float)r10; o[5] = (float)r11; o[6]  = (float)r12;
    o[7] = (float)(-(r10*t0 + r11*t1 + r12*t2));
    o[8] = (float)r20; o[9] = (float)r21; o[10] = (float)r22;
    o[11] = (float)(-(r20*t0 + r21*t1 + r22*t2));
}

// ---------------------------------------------------------------------------
// Kernel 1: prep. W (123x256) -> split-bf16 pair whi/wlo, row-major [o][k],
// o zero-padded to 128 (same 128 KB footprint as the old fp32 wt2).
// Block 0 also inverts cam2ego.
// ---------------------------------------------------------------------------
__global__ __launch_bounds__(256) void k_pre(
    const float* __restrict__ wd, const float* __restrict__ c2e,
    unsigned short* __restrict__ whi, unsigned short* __restrict__ wlo,
    float* __restrict__ e2c) {
    const int o = blockIdx.x;   // 0..127
    const int k = threadIdx.x;  // 0..255
    float f = (o < NOUT) ? wd[(size_t)o * CI + k] : 0.f;
    unsigned short hi = f2bf(f);
    whi[o * 256 + k] = hi;
    wlo[o * 256 + k] = f2bf(f - bf2f(hi));
    if (blockIdx.x == 0 && k < NB * NC)
        inv_rigid(c2e + k * 16, e2c + k * 12);
}

// ---------------------------------------------------------------------------
// Kernel 2: depth/feat head on the MATRIX CORES (split-bf16, fp32-accurate).
// After 7 VALU restructures all pinned at ~36 us (floor ~10), the untried
// mechanism was MFMA (guide G10): X = Whi*Bhi + Whi*Blo + Wlo*Bhi with
// a = a_hi + a_lo bf16 split (dropped lo*lo term ~4e-6 abs — invisible).
// 256 blocks x 512 thr (8 waves = 8 o-tiles of 16). Stage A once: 66 px x
// 256 ch split to bf16 hi/lo in XOR-swizzled LDS (si ^= (px&7)<<3 kills the
// 16-way stride-512B conflict on fragment ds_read_b128). Per wave: 8 K-steps
// x { 2x 16B global W-frag loads (L2-hot, 5x reuse) x 5 px-tiles x
// (2 ds_read + 3 mfma_f32_16x16x32_bf16) } = 120 MFMA, zero k-loop barriers.
// Fragment layouts: A row=lane&15, k=(lane>>4)*8+j; B col=lane&15 same k;
// C/D col=lane&15, row=(lane>>4)*4+reg (m89-verified).
// px-tile 4 covers px 64..79: lanes lm>=2 read a clamped valid row and their
// results are never written. Epilogue (feat/softmax/depth) = R0 form.
// ---------------------------------------------------------------------------
__global__ __launch_bounds__(512) void k_head(
    const float* __restrict__ img, const unsigned short* __restrict__ whi_g,
    const unsigned short* __restrict__ wlo_g, const float* __restrict__ bd,
    float* __restrict__ depth_out, float* __restrict__ feat_ws) {
    __shared__ __align__(16) unsigned short Bbuf[2 * PXB * 256]; // 67.6 KB
    __shared__ float S[PXB];
    unsigned short* BH = Bbuf;
    unsigned short* BL = Bbuf + PXB * 256;

    const int tid = threadIdx.x;
    const int wv  = tid >> 6;            // 0..7 -> o-tile
    const int ln  = tid & 63;
    const int lm  = ln & 15;             // fragment row/col lane index
    const int lg  = ln >> 4;             // k-group
    const int p0  = blockIdx.x * PXB;

    // ---- stage A tile, split to bf16 hi/lo, swizzled: 33*512 = 16896 ----
    for (int it = 0; it < 33; ++it) {
        int idx = tid + it * 512;
        int c = idx / PXB, px = idx - c * PXB;
        int p = p0 + px;
        int bn = p / HW, hw = p - bn * HW;
        float f = img[((size_t)bn * CI + c) * HW + hw];
        unsigned short hi = f2bf(f);
        unsigned short lo = f2bf(f - bf2f(hi));
        int si = (px * 256 + c) ^ ((px & 7) << 3);
        BH[si] = hi;
        BL[si] = lo;
    }
    __syncthreads();

    // ---- MFMA main loop: no barriers ----
    f32x4 acc[5];
#pragma unroll
    for (int t = 0; t < 5; ++t) acc[t] = (f32x4)(0.f);

    int pxs[5];
#pragma unroll
    for (int t = 0; t < 4; ++t) pxs[t] = t * 16 + lm;
    pxs[4] = (lm < 2) ? (64 + lm) : 65;          // clamp: valid row, unused out

    const unsigned short* wh = whi_g + (size_t)(wv * 16 + lm) * 256;
    const unsigned short* wl = wlo_g + (size_t)(wv * 16 + lm) * 256;

#pragma unroll
    for (int s = 0; s < 8; ++s) {
        const int kk = s * 32 + lg * 8;
        short8 a_hi = *(const short8*)(wh + kk);   // 16B, L2-hot, 5x reuse
        short8 a_lo = *(const short8*)(wl + kk);
#pragma unroll
        for (int t = 0; t < 5; ++t) {
            int si = (pxs[t] * 256 + kk) ^ ((pxs[t] & 7) << 3);
            short8 b_hi = *(const short8*)(BH + si);
            short8 b_lo = *(const short8*)(BL + si);
            acc[t] = __builtin_amdgcn_mfma_f32_16x16x32_bf16(a_hi, b_hi, acc[t], 0, 0, 0);
            acc[t] = __builtin_amdgcn_mfma_f32_16x16x32_bf16(a_hi, b_lo, acc[t], 0, 0, 0);
            acc[t] = __builtin_amdgcn_mfma_f32_16x16x32_bf16(a_lo, b_hi, acc[t], 0, 0, 0);
        }
    }
    __syncthreads();          // all B reads done -> X may alias Bbuf

    // ---- epilogue into X[66][132]: logits col o (<59), feat col o+5 ----
    float* X = (float*)Bbuf;  // 66*132*4 = 34.8 KB < 67.6 KB
    const int ob = wv * 16 + lg * 4;     // o base for this lane's regs
#pragma unroll
    for (int t = 0; t < 5; ++t) {
        int px = t * 16 + lm;
        if (px < PXB) {
#pragma unroll
            for (int r = 0; r < 4; ++r) {
                int o = ob + r;
                if (o < NOUT) {
                    int col = (o < D_BINS) ? o : o + 5;
                    X[px * 132 + col] = acc[t][r] + bd[o];
                }
            }
        }
    }
    __syncthreads();

    // feat: X[p][64..127] -> feat_ws, coalesced float4 (1056 of them)
    for (int g = tid; g < PXB * 16; g += 512) {
        int p = g >> 4, m = g & 15;
        float4 v = *(const float4*)(X + p * 132 + 64 + m * 4);
        *(float4*)(feat_ws + (size_t)(p0 + p) * CO + m * 4) = v;
    }

    // softmax over cols 0..58, one thread per pixel (R0 form)
    if (tid < PXB) {
        float* row = X + tid * 132;
        float m = row[0];
        for (int o = 1; o < D_BINS; ++o) m = fmaxf(m, row[o]);
        float s = 0.f;
        for (int o = 0; o < D_BINS; ++o) {
            float e = __expf(row[o] - m);
            row[o] = e;
            s += e;
        }
        S[tid] = 1.f / s;
    }
    __syncthreads();

    // depth: block region contiguous [p0*59, (p0+66)*59) -> coalesced
    for (int g = tid; g < PXB * D_BINS; g += 512) {
        int p = g / D_BINS;
        int o = g - p * D_BINS;
        depth_out[(size_t)p0 * D_BINS + g] = X[p * 132 + o] * S[p];
    }
}

// ---------------------------------------------------------------------------
// Kernel 3: project voxels, gather depth weight + feat, splat to BEV.
// Round-0 (124 us baseline) version, byte-identical.
// ---------------------------------------------------------------------------
__global__ __launch_bounds__(256) void k_splat(
    const float* __restrict__ e2c, const float* __restrict__ Kmat,
    const float* __restrict__ depth_g, const float* __restrict__ feat_ws,
    float* __restrict__ bev) {
    __shared__ int   hw_s[ZD][64];
    __shared__ float wgt_s[ZD][64];

    const int tx = threadIdx.x;          // 0..63 -> x
    const int cq = threadIdx.y;          // 0..3  -> channel quarter / z-slice
    const int x = blockIdx.x * 64 + tx;
    const int y = blockIdx.y;
    const int b = blockIdx.z;
    const float wx = (float)x * 0.8f + (-51.2f);
    const float wy = (float)y * 0.8f + (-51.2f);

    float acc[16];
#pragma unroll
    for (int m = 0; m < 16; ++m) acc[m] = 0.f;

    for (int n = 0; n < NC; ++n) {
        const int bn = b * NC + n;
        const float* E = e2c + bn * 12;
        const float* Km = Kmat + bn * 9;
        const float k00 = Km[0], k01 = Km[1], k02 = Km[2];
        const float k10 = Km[3], k11 = Km[4], k12 = Km[5];
        const float e02 = E[2], e12 = E[6], e22 = E[10];
        const float bx0 = E[0] * wx + E[1] * wy + E[3];
        const float bx1 = E[4] * wx + E[5] * wy + E[7];
        const float bx2 = E[8] * wx + E[9] * wy + E[11];

        // ---- projection phase: thread (tx,cq) owns z = cq and cq+4 ----
#pragma unroll
        for (int zz = 0; zz < 2; ++zz) {
            const int z = cq + zz * 4;
            if (z < ZD) {
                const float wz = -2.5f + (float)z;
                const float cx = bx0 + e02 * wz;
                const float cy = bx1 + e12 * wz;
                const float cz = bx2 + e22 * wz;
                const float zs = fmaxf(cz, 0.1f);
                const float rz = 1.0f / zs;         // IEEE divide
                const float xn = cx * rz;
                const float yn = cy * rz;
                const float fu = (k00 * xn + k01 * yn + k02) * 0.0625f;
                const float fv = (k10 * xn + k11 * yn + k12) * 0.0625f;
                const int bin = (int)(cz - 1.0f);   // trunc, matches astype(int32)
                const bool valid = (fu >= 0.f) & (fu < (float)W_IMG) &
                                   (fv >= 0.f) & (fv < (float)H_IMG) &
                                   (cz > 0.5f) & (bin >= 0) & (bin < D_BINS);
                int hw = -1;
                float wgt = 0.f;
                if (valid) {
                    int u = (int)fu;                // valid => in range
                    int v = (int)fv;
                    hw = v * W_IMG + u;
                    wgt = depth_g[((size_t)bn * HW + hw) * D_BINS + bin];
                }
                hw_s[z][tx] = hw;
                wgt_s[z][tx] = wgt;
            }
        }
        __syncthreads();

        // ---- accumulate phase: z ascending (same FMA order as baseline) ----
#pragma unroll
        for (int z = 0; z < ZD; ++z) {
            const int hw = hw_s[z][tx];       // 4 cq threads same addr: broadcast
            if (hw >= 0) {
                const float wgt = wgt_s[z][tx];
                const float4* fp =
                    (const float4*)(feat_ws + ((size_t)bn * HW + hw) * CO + cq * 16);
                float4 f0 = fp[0], f1 = fp[1], f2 = fp[2], f3 = fp[3];
                acc[0]  = fmaf(wgt, f0.x, acc[0]);
                acc[1]  = fmaf(wgt, f0.y, acc[1]);
                acc[2]  = fmaf(wgt, f0.z, acc[2]);
                acc[3]  = fmaf(wgt, f0.w, acc[3]);
                acc[4]  = fmaf(wgt, f1.x, acc[4]);
                acc[5]  = fmaf(wgt, f1.y, acc[5]);
                acc[6]  = fmaf(wgt, f1.z, acc[6]);
                acc[7]  = fmaf(wgt, f1.w, acc[7]);
                acc[8]  = fmaf(wgt, f2.x, acc[8]);
                acc[9]  = fmaf(wgt, f2.y, acc[9]);
                acc[10] = fmaf(wgt, f2.z, acc[10]);
                acc[11] = fmaf(wgt, f2.w, acc[11]);
                acc[12] = fmaf(wgt, f3.x, acc[12]);
                acc[13] = fmaf(wgt, f3.y, acc[13]);
                acc[14] = fmaf(wgt, f3.z, acc[14]);
                acc[15] = fmaf(wgt, f3.w, acc[15]);
            }
        }
        __syncthreads();   // LDS reused next n
    }
    // out[b][c][y][x], c = cq*16 + m; 64 lanes = consecutive x -> coalesced
    float* ob = bev + (((size_t)b * CO + cq * 16) * YD + y) * XD + x;
#pragma unroll
    for (int m = 0; m < 16; ++m) ob[(size_t)m * YD * XD] = acc[m];
}

extern "C" void kernel_launch(void* const* d_in, const int* in_sizes, int n_in,
                              void* d_out, int out_size, void* d_ws, size_t ws_size,
                              hipStream_t stream) {
    const float* img  = (const float*)d_in[0];  // (B,N,256,16,44)
    const float* c2e  = (const float*)d_in[1];  // (B,N,4,4)
    const float* Kmat = (const float*)d_in[2];  // (B,N,3,3)
    const float* wd   = (const float*)d_in[3];  // (123,256)
    const float* bd   = (const float*)d_in[4];  // (123,)
    float* bev = (float*)d_out;                         // (B,64,128,128)
    float* depth_out = bev + (size_t)NB * CO * YD * XD; // (B,N,16,44,59)
    float* feat_ws = (float*)d_ws;                      // NPIX*64 floats
    unsigned short* whi = (unsigned short*)(feat_ws + (size_t)NPIX * CO); // 64KB
    unsigned short* wlo = whi + 128 * 256;                                // 64KB
    float* e2c = (float*)(wlo + 128 * 256);             // 24*12 floats

    k_pre<<<128, 256, 0, stream>>>(wd, c2e, whi, wlo, e2c);
    k_head<<<256, 512, 0, stream>>>(img, whi, wlo, bd, depth_out, feat_ws);
    k_splat<<<dim3(2, YD, NB), dim3(64, 4, 1), 0, stream>>>(e2c, Kmat, depth_out,
                                                            feat_ws, bev);
}

// Round 13
// 119.231 us; speedup vs baseline: 1.1199x; 1.0142x over previous
//
#include <hip/hip_runtime.h>
#include <math.h>

#define D_BINS 59
#define CO     64
#define CI     256
#define NB     4
#define NC     6
#define H_IMG  16
#define W_IMG  44
#define HW     704            // H_IMG * W_IMG
#define NPIX   (NB*NC*HW)     // 16896
#define XD     128
#define YD     128
#define ZD     7
#define NOUT   123            // D_BINS + CO
#define PXT    64             // pixels per k_head tile: 16896 = 264*64; 704 = 11*64
#define NTILE  264

typedef float v2f  __attribute__((ext_vector_type(2)));
typedef short short8 __attribute__((ext_vector_type(8)));
typedef float f32x4  __attribute__((ext_vector_type(4)));

// round-to-nearest-even fp32 -> bf16 (bit pattern), and back
__device__ inline unsigned short f2bf(float f) {
    unsigned u = __float_as_uint(f);
    return (unsigned short)((u + 0x7FFFu + ((u >> 16) & 1u)) >> 16);
}
__device__ inline float bf2f(unsigned short h) {
    return __uint_as_float((unsigned)h << 16);
}

// ---------------------------------------------------------------------------
// Double-precision rigid-transform inverse (matches np.linalg.inv to ~1e-15).
// ---------------------------------------------------------------------------
__device__ void inv_rigid(const float* __restrict__ M, float* __restrict__ o) {
    double a = M[0], b = M[1], c = M[2], t0 = M[3];
    double d = M[4], e = M[5], f = M[6], t1 = M[7];
    double g = M[8], h = M[9], ii = M[10], t2 = M[11];
    double A00 = e*ii - f*h, A01 = c*h - b*ii, A02 = b*f - c*e;
    double A10 = f*g - d*ii, A11 = a*ii - c*g, A12 = c*d - a*f;
    double A20 = d*h - e*g,  A21 = b*g - a*h,  A22 = a*e - b*d;
    double det = a*A00 + b*A10 + c*A20;
    double inv = 1.0 / det;
    double r00 = A00*inv, r01 = A01*inv, r02 = A02*inv;
    double r10 = A10*inv, r11 = A11*inv, r12 = A12*inv;
    double r20 = A20*inv, r21 = A21*inv, r22 = A22*inv;
    o[0] = (float)r00; o[1] = (float)r01; o[2]  = (float)r02;
    o[3] = (float)(-(r00*t0 + r01*t1 + r02*t2));
    o[4] = (float)r10; o[5] = (float)r11; o[6]  = (float)r12;
    o[7] = (float)(-(r10*t0 + r11*t1 + r12*t2));
    o[8] = (float)r20; o[9] = (float)r21; o[10] = (float)r22;
    o[11] = (float)(-(r20*t0 + r21*t1 + r22*t2));
}

// ---------------------------------------------------------------------------
// Kernel 1: prep. W (123x256) -> split-bf16 pair whi/wlo, row-major [o][k],
// o zero-padded to 128. Block 0 also inverts cam2ego. Unchanged from R12.
// ---------------------------------------------------------------------------
__global__ __launch_bounds__(256) void k_pre(
    const float* __restrict__ wd, const float* __restrict__ c2e,
    unsigned short* __restrict__ whi, unsigned short* __restrict__ wlo,
    float* __restrict__ e2c) {
    const int o = blockIdx.x;   // 0..127
    const int k = threadIdx.x;  // 0..255
    float f = (o < NOUT) ? wd[(size_t)o * CI + k] : 0.f;
    unsigned short hi = f2bf(f);
    whi[o * 256 + k] = hi;
    wlo[o * 256 + k] = f2bf(f - bf2f(hi));
    if (blockIdx.x == 0 && k < NB * NC)
        inv_rigid(c2e + k * 16, e2c + k * 12);
}

// ---------------------------------------------------------------------------
// Kernel 2: MFMA depth/feat head (split-bf16), R12 math, NEW staging:
// VECTORIZED img loads. All 8 prior k_head variants (incl. R12 MFMA) staged
// img with per-thread SCALAR dword loads — Common-mistake #2. R6's direct
// row (597 GB/s, VALUBusy 30%) says k_head is latency-pinned, and scalar
// load count is the invariant. Now: tile = 64 px (264 tiles; 704 = 11*64 ->
// hw0 64-aligned, tiles never cross a camera), staging = 8 ALIGNED float4
// loads/thread (issue-all-then-convert) instead of 33 scalar dwords.
// 4 px-tiles/wave exactly (no clamp), 96 mfma_f32_16x16x32_bf16 per wave.
// Same LDS swizzle both sides: si = (px*256+c) ^ ((px&7)<<3).
// Per-pixel K-order identical to R12 -> same absmax (~0.0039, passed).
// ---------------------------------------------------------------------------
__global__ __launch_bounds__(512) void k_head(
    const float* __restrict__ img, const unsigned short* __restrict__ whi_g,
    const unsigned short* __restrict__ wlo_g, const float* __restrict__ bd,
    float* __restrict__ depth_out, float* __restrict__ feat_ws) {
    __shared__ __align__(16) unsigned short Bbuf[2 * PXT * 256]; // 64 KB
    __shared__ float S[PXT];
    unsigned short* BH = Bbuf;
    unsigned short* BL = Bbuf + PXT * 256;

    const int tid = threadIdx.x;
    const int wv  = tid >> 6;            // 0..7 -> o-tile
    const int ln  = tid & 63;
    const int lm  = ln & 15;             // fragment row/col lane index
    const int lg  = ln >> 4;             // k-group
    const int p0  = blockIdx.x * PXT;

    const int bn  = p0 / HW;             // tile within one (b,n): 704 = 11*64
    const int hw0 = p0 - bn * HW;        // 64-aligned
    const float* gsrc = img + (size_t)bn * CI * HW + hw0;

    // ---- stage A tile: 4096 aligned float4s, 8 per thread ----
    float4 rv[8];
#pragma unroll
    for (int it = 0; it < 8; ++it) {
        int idx = tid + it * 512;        // < 4096
        int c = idx >> 4, f4 = idx & 15; // 16 float4 per channel row
        rv[it] = *(const float4*)(gsrc + (size_t)c * HW + f4 * 4);
    }
#pragma unroll
    for (int it = 0; it < 8; ++it) {
        int idx = tid + it * 512;
        int c = idx >> 4, f4 = idx & 15;
        int px = f4 * 4;
        float e[4] = { rv[it].x, rv[it].y, rv[it].z, rv[it].w };
#pragma unroll
        for (int q = 0; q < 4; ++q) {
            int pxe = px + q;
            unsigned short hi = f2bf(e[q]);
            unsigned short lo = f2bf(e[q] - bf2f(hi));
            int si = (pxe * 256 + c) ^ ((pxe & 7) << 3);
            BH[si] = hi;
            BL[si] = lo;
        }
    }
    __syncthreads();

    // ---- MFMA main loop: no barriers ----
    f32x4 acc[4];
#pragma unroll
    for (int t = 0; t < 4; ++t) acc[t] = (f32x4)(0.f);

    const unsigned short* wh = whi_g + (size_t)(wv * 16 + lm) * 256;
    const unsigned short* wl = wlo_g + (size_t)(wv * 16 + lm) * 256;

#pragma unroll
    for (int s = 0; s < 8; ++s) {
        const int kk = s * 32 + lg * 8;
        short8 a_hi = *(const short8*)(wh + kk);   // 16B, L2-hot, 4x reuse
        short8 a_lo = *(const short8*)(wl + kk);
#pragma unroll
        for (int t = 0; t < 4; ++t) {
            int px = t * 16 + lm;
            int si = (px * 256 + kk) ^ ((px & 7) << 3);
            short8 b_hi = *(const short8*)(BH + si);
            short8 b_lo = *(const short8*)(BL + si);
            acc[t] = __builtin_amdgcn_mfma_f32_16x16x32_bf16(a_hi, b_hi, acc[t], 0, 0, 0);
            acc[t] = __builtin_amdgcn_mfma_f32_16x16x32_bf16(a_hi, b_lo, acc[t], 0, 0, 0);
            acc[t] = __builtin_amdgcn_mfma_f32_16x16x32_bf16(a_lo, b_hi, acc[t], 0, 0, 0);
        }
    }
    __syncthreads();          // all B reads done -> X may alias Bbuf

    // ---- epilogue into X[64][132]: logits col o (<59), feat col o+5 ----
    float* X = (float*)Bbuf;  // 64*132*4 = 33.8 KB < 64 KB
    const int ob = wv * 16 + lg * 4;     // o base for this lane's regs
#pragma unroll
    for (int t = 0; t < 4; ++t) {
        int px = t * 16 + lm;
#pragma unroll
        for (int r = 0; r < 4; ++r) {
            int o = ob + r;
            if (o < NOUT) {
                int col = (o < D_BINS) ? o : o + 5;
                X[px * 132 + col] = acc[t][r] + bd[o];
            }
        }
    }
    __syncthreads();

    // feat: X[p][64..127] -> feat_ws, coalesced float4 (1024 of them)
    for (int g = tid; g < PXT * 16; g += 512) {
        int p = g >> 4, m = g & 15;
        float4 v = *(const float4*)(X + p * 132 + 64 + m * 4);
        *(float4*)(feat_ws + (size_t)(p0 + p) * CO + m * 4) = v;
    }

    // softmax over cols 0..58, one thread per pixel (R0 form)
    if (tid < PXT) {
        float* row = X + tid * 132;
        float m = row[0];
        for (int o = 1; o < D_BINS; ++o) m = fmaxf(m, row[o]);
        float s = 0.f;
        for (int o = 0; o < D_BINS; ++o) {
            float e = __expf(row[o] - m);
            row[o] = e;
            s += e;
        }
        S[tid] = 1.f / s;
    }
    __syncthreads();

    // depth: tile region contiguous [p0*59, (p0+64)*59) -> coalesced
    for (int g = tid; g < PXT * D_BINS; g += 512) {
        int p = g / D_BINS;
        int o = g - p * D_BINS;
        depth_out[(size_t)p0 * D_BINS + g] = X[p * 132 + o] * S[p];
    }
}

// ---------------------------------------------------------------------------
// Kernel 3: project voxels, gather depth weight + feat, splat to BEV.
// Round-0 (124 us baseline) version, byte-identical.
// ---------------------------------------------------------------------------
__global__ __launch_bounds__(256) void k_splat(
    const float* __restrict__ e2c, const float* __restrict__ Kmat,
    const float* __restrict__ depth_g, const float* __restrict__ feat_ws,
    float* __restrict__ bev) {
    __shared__ int   hw_s[ZD][64];
    __shared__ float wgt_s[ZD][64];

    const int tx = threadIdx.x;          // 0..63 -> x
    const int cq = threadIdx.y;          // 0..3  -> channel quarter / z-slice
    const int x = blockIdx.x * 64 + tx;
    const int y = blockIdx.y;
    const int b = blockIdx.z;
    const float wx = (float)x * 0.8f + (-51.2f);
    const float wy = (float)y * 0.8f + (-51.2f);

    float acc[16];
#pragma unroll
    for (int m = 0; m < 16; ++m) acc[m] = 0.f;

    for (int n = 0; n < NC; ++n) {
        const int bn = b * NC + n;
        const float* E = e2c + bn * 12;
        const float* Km = Kmat + bn * 9;
        const float k00 = Km[0], k01 = Km[1], k02 = Km[2];
        const float k10 = Km[3], k11 = Km[4], k12 = Km[5];
        const float e02 = E[2], e12 = E[6], e22 = E[10];
        const float bx0 = E[0] * wx + E[1] * wy + E[3];
        const float bx1 = E[4] * wx + E[5] * wy + E[7];
        const float bx2 = E[8] * wx + E[9] * wy + E[11];

        // ---- projection phase: thread (tx,cq) owns z = cq and cq+4 ----
#pragma unroll
        for (int zz = 0; zz < 2; ++zz) {
            const int z = cq + zz * 4;
            if (z < ZD) {
                const float wz = -2.5f + (float)z;
                const float cx = bx0 + e02 * wz;
                const float cy = bx1 + e12 * wz;
                const float cz = bx2 + e22 * wz;
                const float zs = fmaxf(cz, 0.1f);
                const float rz = 1.0f / zs;         // IEEE divide
                const float xn = cx * rz;
                const float yn = cy * rz;
                const float fu = (k00 * xn + k01 * yn + k02) * 0.0625f;
                const float fv = (k10 * xn + k11 * yn + k12) * 0.0625f;
                const int bin = (int)(cz - 1.0f);   // trunc, matches astype(int32)
                const bool valid = (fu >= 0.f) & (fu < (float)W_IMG) &
                                   (fv >= 0.f) & (fv < (float)H_IMG) &
                                   (cz > 0.5f) & (bin >= 0) & (bin < D_BINS);
                int hw = -1;
                float wgt = 0.f;
                if (valid) {
                    int u = (int)fu;                // valid => in range
                    int v = (int)fv;
                    hw = v * W_IMG + u;
                    wgt = depth_g[((size_t)bn * HW + hw) * D_BINS + bin];
                }
                hw_s[z][tx] = hw;
                wgt_s[z][tx] = wgt;
            }
        }
        __syncthreads();

        // ---- accumulate phase: z ascending (same FMA order as baseline) ----
#pragma unroll
        for (int z = 0; z < ZD; ++z) {
            const int hw = hw_s[z][tx];       // 4 cq threads same addr: broadcast
            if (hw >= 0) {
                const float wgt = wgt_s[z][tx];
                const float4* fp =
                    (const float4*)(feat_ws + ((size_t)bn * HW + hw) * CO + cq * 16);
                float4 f0 = fp[0], f1 = fp[1], f2 = fp[2], f3 = fp[3];
                acc[0]  = fmaf(wgt, f0.x, acc[0]);
                acc[1]  = fmaf(wgt, f0.y, acc[1]);
                acc[2]  = fmaf(wgt, f0.z, acc[2]);
                acc[3]  = fmaf(wgt, f0.w, acc[3]);
                acc[4]  = fmaf(wgt, f1.x, acc[4]);
                acc[5]  = fmaf(wgt, f1.y, acc[5]);
                acc[6]  = fmaf(wgt, f1.z, acc[6]);
                acc[7]  = fmaf(wgt, f1.w, acc[7]);
                acc[8]  = fmaf(wgt, f2.x, acc[8]);
                acc[9]  = fmaf(wgt, f2.y, acc[9]);
                acc[10] = fmaf(wgt, f2.z, acc[10]);
                acc[11] = fmaf(wgt, f2.w, acc[11]);
                acc[12] = fmaf(wgt, f3.x, acc[12]);
                acc[13] = fmaf(wgt, f3.y, acc[13]);
                acc[14] = fmaf(wgt, f3.z, acc[14]);
                acc[15] = fmaf(wgt, f3.w, acc[15]);
            }
        }
        __syncthreads();   // LDS reused next n
    }
    // out[b][c][y][x], c = cq*16 + m; 64 lanes = consecutive x -> coalesced
    float* ob = bev + (((size_t)b * CO + cq * 16) * YD + y) * XD + x;
#pragma unroll
    for (int m = 0; m < 16; ++m) ob[(size_t)m * YD * XD] = acc[m];
}

extern "C" void kernel_launch(void* const* d_in, const int* in_sizes, int n_in,
                              void* d_out, int out_size, void* d_ws, size_t ws_size,
                              hipStream_t stream) {
    const float* img  = (const float*)d_in[0];  // (B,N,256,16,44)
    const float* c2e  = (const float*)d_in[1];  // (B,N,4,4)
    const float* Kmat = (const float*)d_in[2];  // (B,N,3,3)
    const float* wd   = (const float*)d_in[3];  // (123,256)
    const float* bd   = (const float*)d_in[4];  // (123,)
    float* bev = (float*)d_out;                         // (B,64,128,128)
    float* depth_out = bev + (size_t)NB * CO * YD * XD; // (B,N,16,44,59)
    float* feat_ws = (float*)d_ws;                      // NPIX*64 floats
    unsigned short* whi = (unsigned short*)(feat_ws + (size_t)NPIX * CO); // 64KB
    unsigned short* wlo = whi + 128 * 256;                                // 64KB
    float* e2c = (float*)(wlo + 128 * 256);             // 24*12 floats

    k_pre<<<128, 256, 0, stream>>>(wd, c2e, whi, wlo, e2c);
    k_head<<<NTILE, 512, 0, stream>>>(img, whi, wlo, bd, depth_out, feat_ws);
    k_splat<<<dim3(2, YD, NB), dim3(64, 4, 1), 0, stream>>>(e2c, Kmat, depth_out,
                                                            feat_ws, bev);
}